// Round 1
// baseline (388.355 us; speedup 1.0000x reference)
//
#include <hip/hip_runtime.h>

#define NROWS 4096
#define DMODEL 256
#define NHEADS 8
#define HD 32

// ---------------- GEMM: C[M x Nd] = A[M x Kd] @ B[Nd x Kd]^T + bias -------
// BM=BN=64, BK=16, 256 threads, 4x4 micro-tile per thread.
#define BM 64
#define BN 64
#define BK 16

template<bool SCATTER>
__global__ __launch_bounds__(256) void gemm_bt(
    const float* __restrict__ A, const float* __restrict__ B,
    const float* __restrict__ bias, float* __restrict__ C,
    float* __restrict__ Qo, float* __restrict__ Ko, float* __restrict__ Vo,
    int Kd, int Nd) {
  __shared__ float As[BK][BM];
  __shared__ float Bs[BK][BN];
  const int tid = threadIdx.x;
  const int bm = blockIdx.y * BM;
  const int bn = blockIdx.x * BN;
  const int tx = tid & 15, ty = tid >> 4;
  const int lr = tid >> 2;          // row within tile (0..63)
  const int lc = (tid & 3) << 2;    // k-col offset (0,4,8,12)
  float acc[4][4] = {};
  for (int k0 = 0; k0 < Kd; k0 += BK) {
    float4 a4 = *(const float4*)(A + (size_t)(bm + lr) * Kd + k0 + lc);
    float4 b4 = *(const float4*)(B + (size_t)(bn + lr) * Kd + k0 + lc);
    As[lc + 0][lr] = a4.x; As[lc + 1][lr] = a4.y;
    As[lc + 2][lr] = a4.z; As[lc + 3][lr] = a4.w;
    Bs[lc + 0][lr] = b4.x; Bs[lc + 1][lr] = b4.y;
    Bs[lc + 2][lr] = b4.z; Bs[lc + 3][lr] = b4.w;
    __syncthreads();
    #pragma unroll
    for (int kk = 0; kk < BK; kk++) {
      float4 av = *(const float4*)&As[kk][ty << 2];
      float4 bv = *(const float4*)&Bs[kk][tx << 2];
      float ar[4] = {av.x, av.y, av.z, av.w};
      float br[4] = {bv.x, bv.y, bv.z, bv.w};
      #pragma unroll
      for (int i = 0; i < 4; i++)
        #pragma unroll
        for (int j = 0; j < 4; j++) acc[i][j] += ar[i] * br[j];
    }
    __syncthreads();
  }
  #pragma unroll
  for (int i = 0; i < 4; i++) {
    const int n = bm + (ty << 2) + i;
    #pragma unroll
    for (int j = 0; j < 4; j++) {
      const int col = bn + (tx << 2) + j;
      float v = acc[i][j] + bias[col];
      if (SCATTER) {
        // col in [0,768): 0..255 -> Q, 256..511 -> K, 512..767 -> V
        const int sel = col >> 8;
        const int h = (col & 255) >> 5;
        const int d = col & 31;
        float* dst = (sel == 0) ? Qo : (sel == 1) ? Ko : Vo;
        dst[((size_t)h * NROWS + n) * HD + d] = v;
      } else {
        C[(size_t)n * Nd + col] = v;
      }
    }
  }
}

// ---------------- Attention: one wave per (row, head) ----------------------
// batch_idx is sorted, so the attend-set is a contiguous segment found by
// binary search. Online softmax per lane over strided columns; butterfly
// combine across the 64 lanes at the end.
__global__ __launch_bounds__(256) void attn_kernel(
    const float* __restrict__ Q, const float* __restrict__ K,
    const float* __restrict__ V, const int* __restrict__ bidx,
    float* __restrict__ out /* [N][D] head-major cols */) {
  const int wid = blockIdx.x * 4 + (threadIdx.x >> 6);
  const int lane = threadIdx.x & 63;
  const int n = wid >> 3;
  const int h = wid & 7;

  const int b = bidx[n];
  int lo = 0, hi = NROWS;
  while (lo < hi) { int mid = (lo + hi) >> 1; if (bidx[mid] < b) lo = mid + 1; else hi = mid; }
  const int start = lo;
  lo = 0; hi = NROWS;
  while (lo < hi) { int mid = (lo + hi) >> 1; if (bidx[mid] <= b) lo = mid + 1; else hi = mid; }
  const int end = lo;

  const float scale = 0.17677669529663687f;  // 1/sqrt(32)

  float q[HD];
  {
    const float4* qp = (const float4*)(Q + ((size_t)h * NROWS + n) * HD);
    #pragma unroll
    for (int i = 0; i < 8; i++) {
      float4 t = qp[i];
      q[i * 4 + 0] = t.x; q[i * 4 + 1] = t.y; q[i * 4 + 2] = t.z; q[i * 4 + 3] = t.w;
    }
  }

  float m_i = -1e30f, l_i = 0.0f;
  float o[HD];
  #pragma unroll
  for (int d = 0; d < HD; d++) o[d] = 0.0f;

  for (int mcol = start + lane; mcol < end; mcol += 64) {
    const float4* kp = (const float4*)(K + ((size_t)h * NROWS + mcol) * HD);
    const float4* vp = (const float4*)(V + ((size_t)h * NROWS + mcol) * HD);
    float s = 0.0f;
    #pragma unroll
    for (int i = 0; i < 8; i++) {
      float4 kv = kp[i];
      s += q[i * 4 + 0] * kv.x + q[i * 4 + 1] * kv.y +
           q[i * 4 + 2] * kv.z + q[i * 4 + 3] * kv.w;
    }
    s *= scale;
    const float newm = fmaxf(m_i, s);
    const float p = __expf(s - newm);
    const float f = __expf(m_i - newm);
    l_i = l_i * f + p;
    #pragma unroll
    for (int i = 0; i < 8; i++) {
      float4 vv = vp[i];
      o[i * 4 + 0] = o[i * 4 + 0] * f + p * vv.x;
      o[i * 4 + 1] = o[i * 4 + 1] * f + p * vv.y;
      o[i * 4 + 2] = o[i * 4 + 2] * f + p * vv.z;
      o[i * 4 + 3] = o[i * 4 + 3] * f + p * vv.w;
    }
    m_i = newm;
  }

  // cross-lane combine
  float M = m_i;
  #pragma unroll
  for (int off = 32; off; off >>= 1) M = fmaxf(M, __shfl_xor(M, off));
  const float f = __expf(m_i - M);
  l_i *= f;
  #pragma unroll
  for (int d = 0; d < HD; d++) o[d] *= f;
  #pragma unroll
  for (int off = 32; off; off >>= 1) l_i += __shfl_xor(l_i, off);
  #pragma unroll
  for (int d = 0; d < HD; d++) {
    #pragma unroll
    for (int off = 32; off; off >>= 1) o[d] += __shfl_xor(o[d], off);
  }
  if (lane == 0) {
    const float inv = 1.0f / l_i;
    float* op = out + (size_t)n * DMODEL + h * HD;
    #pragma unroll
    for (int d = 0; d < HD; d++) op[d] = o[d] * inv;
  }
}

// ---------------- Residual + LayerNorm, one block (256 thr) per row --------
__global__ __launch_bounds__(256) void ln_kernel(
    const float* __restrict__ x, const float* __restrict__ delta,
    const float* __restrict__ gamma, const float* __restrict__ beta,
    float* __restrict__ out) {
  const int n = blockIdx.x;
  const int t = threadIdx.x;
  __shared__ float red[8];
  const float v = x[(size_t)n * DMODEL + t] + delta[(size_t)n * DMODEL + t];
  float s = v;
  #pragma unroll
  for (int off = 32; off; off >>= 1) s += __shfl_xor(s, off);
  const int w = t >> 6;
  if ((t & 63) == 0) red[w] = s;
  __syncthreads();
  const float mean = (red[0] + red[1] + red[2] + red[3]) * (1.0f / DMODEL);
  const float d0 = v - mean;
  float s2 = d0 * d0;
  #pragma unroll
  for (int off = 32; off; off >>= 1) s2 += __shfl_xor(s2, off);
  if ((t & 63) == 0) red[4 + w] = s2;
  __syncthreads();
  const float var = (red[4] + red[5] + red[6] + red[7]) * (1.0f / DMODEL);
  out[(size_t)n * DMODEL + t] = d0 * rsqrtf(var + 1e-5f) * gamma[t] + beta[t];
}

extern "C" void kernel_launch(void* const* d_in, const int* in_sizes, int n_in,
                              void* d_out, int out_size, void* d_ws, size_t ws_size,
                              hipStream_t stream) {
  const float* slots  = (const float*)d_in[0];  // [1, N, D]
  const int*   bidx   = (const int*)  d_in[1];  // [N]
  const float* w_in   = (const float*)d_in[2];  // [768, 256]
  const float* b_in   = (const float*)d_in[3];  // [768]
  const float* w_out  = (const float*)d_in[4];  // [256, 256]
  const float* b_out  = (const float*)d_in[5];  // [256]
  const float* ln_g   = (const float*)d_in[6];  // [256]
  const float* ln_b   = (const float*)d_in[7];  // [256]
  float* out = (float*)d_out;

  float* ws = (float*)d_ws;
  const size_t HN = (size_t)NROWS * HD;  // 131072 floats per head-plane... per head*N*hd
  float* Q    = ws;                       // [H][N][32] = 1,048,576 floats
  float* Kb   = ws + (size_t)NHEADS * HN; // + 1M floats
  float* Vb   = Kb + (size_t)NHEADS * HN; // + 2M floats
  float* attn = Vb + (size_t)NHEADS * HN; // + 3M floats, [N][D]
  float* proj = Q;                        // reuse Q (dead after attention)

  // 1) QKV projection with scatter epilogue
  {
    dim3 grid(768 / BN, NROWS / BM);
    gemm_bt<true><<<grid, 256, 0, stream>>>(slots, w_in, b_in, nullptr,
                                            Q, Kb, Vb, DMODEL, 768);
  }
  // 2) block-diagonal attention
  {
    dim3 grid((NROWS * NHEADS) / 4);
    attn_kernel<<<grid, 256, 0, stream>>>(Q, Kb, Vb, bidx, attn);
  }
  // 3) output projection
  {
    dim3 grid(DMODEL / BN, NROWS / BM);
    gemm_bt<false><<<grid, 256, 0, stream>>>(attn, w_out, b_out, proj,
                                             nullptr, nullptr, nullptr,
                                             DMODEL, DMODEL);
  }
  // 4) residual + layernorm
  ln_kernel<<<NROWS, 256, 0, stream>>>(slots, proj, ln_g, ln_b, out);
}

// Round 2
// 145.559 us; speedup vs baseline: 2.6680x; 2.6680x over previous
//
#include <hip/hip_runtime.h>
#include <hip/hip_bf16.h>

#define NROWS 4096
#define DMODEL 256
#define NHEADS 8
#define HD 32

typedef __attribute__((ext_vector_type(8))) short short8;
typedef __attribute__((ext_vector_type(4))) float f32x4;

// ---------------- GEMM: C[M x Nd] = A[M x Kd] @ B[Nd x Kd]^T + bias -------
// BM=BN=64, BK=16, 256 threads, 4x4 micro-tile per thread. fp32 VALU.
#define BM 64
#define BN 64
#define BK 16

template<bool SCATTER>
__global__ __launch_bounds__(256) void gemm_bt(
    const float* __restrict__ A, const float* __restrict__ B,
    const float* __restrict__ bias, float* __restrict__ C,
    __hip_bfloat16* __restrict__ Qo, __hip_bfloat16* __restrict__ Ko,
    __hip_bfloat16* __restrict__ Vo,   // Vo is TRANSPOSED: [H][HD][N]
    int Kd, int Nd) {
  __shared__ float As[BK][BM];
  __shared__ float Bs[BK][BN];
  const int tid = threadIdx.x;
  const int bm = blockIdx.y * BM;
  const int bn = blockIdx.x * BN;
  const int tx = tid & 15, ty = tid >> 4;
  const int lr = tid >> 2;          // row within tile (0..63)
  const int lc = (tid & 3) << 2;    // k-col offset (0,4,8,12)
  float acc[4][4] = {};
  for (int k0 = 0; k0 < Kd; k0 += BK) {
    float4 a4 = *(const float4*)(A + (size_t)(bm + lr) * Kd + k0 + lc);
    float4 b4 = *(const float4*)(B + (size_t)(bn + lr) * Kd + k0 + lc);
    As[lc + 0][lr] = a4.x; As[lc + 1][lr] = a4.y;
    As[lc + 2][lr] = a4.z; As[lc + 3][lr] = a4.w;
    Bs[lc + 0][lr] = b4.x; Bs[lc + 1][lr] = b4.y;
    Bs[lc + 2][lr] = b4.z; Bs[lc + 3][lr] = b4.w;
    __syncthreads();
    #pragma unroll
    for (int kk = 0; kk < BK; kk++) {
      float4 av = *(const float4*)&As[kk][ty << 2];
      float4 bv = *(const float4*)&Bs[kk][tx << 2];
      float ar[4] = {av.x, av.y, av.z, av.w};
      float br[4] = {bv.x, bv.y, bv.z, bv.w};
      #pragma unroll
      for (int i = 0; i < 4; i++)
        #pragma unroll
        for (int j = 0; j < 4; j++) acc[i][j] += ar[i] * br[j];
    }
    __syncthreads();
  }
  #pragma unroll
  for (int i = 0; i < 4; i++) {
    const int n = bm + (ty << 2) + i;
    #pragma unroll
    for (int j = 0; j < 4; j++) {
      const int col = bn + (tx << 2) + j;
      float v = acc[i][j] + bias[col];
      if (SCATTER) {
        // col in [0,768): 0..255 -> Q, 256..511 -> K, 512..767 -> V (bf16)
        const int sel = col >> 8;
        const int h = (col & 255) >> 5;
        const int d = col & 31;
        __hip_bfloat16 bv16 = __float2bfloat16(v);
        if (sel == 0)      Qo[((size_t)h * NROWS + n) * HD + d] = bv16;
        else if (sel == 1) Ko[((size_t)h * NROWS + n) * HD + d] = bv16;
        else               Vo[((size_t)h * HD + d) * NROWS + n] = bv16;
      } else {
        C[(size_t)n * Nd + col] = v;
      }
    }
  }
}

// ---------------- segment bounds: seg[b] = start, seg[16+b] = end ---------
__global__ void seg_kernel(const int* __restrict__ bidx, int* __restrict__ segs) {
  const int r = blockIdx.x * 256 + threadIdx.x;
  if (r >= NROWS) return;
  const int b = bidx[r];
  if (r == 0 || bidx[r - 1] != b) segs[b] = r;
  if (r == NROWS - 1 || bidx[r + 1] != b) segs[16 + b] = r + 1;
}

// ---------------- MFMA flash attention -------------------------------------
// One wave per (16-row q-tile, head). batch_idx sorted => contiguous segment.
// Per 32-col k-tile: 2 QK mfma (16x16x32) -> masked online softmax (C-layout)
// -> P via wave-private LDS (C-layout -> A-layout) -> 2 PV mfma.
// C/D layout: col=lane&15, row=(lane>>4)*4+reg. A: m=lane&15, k=quad*8+j.
// B: n=lane&15, k=quad*8+j.
__global__ __launch_bounds__(256) void attn_mfma(
    const __hip_bfloat16* __restrict__ Qb,  // [H][N][32]
    const __hip_bfloat16* __restrict__ Kb,  // [H][N][32]
    const __hip_bfloat16* __restrict__ Vt,  // [H][32][N]
    const int* __restrict__ bidx,
    const int* __restrict__ segs,
    float* __restrict__ out)                // [N][256]
{
  __shared__ __align__(16) __hip_bfloat16 Plds_all[4][16][40];  // pad 32->40
  const int wv   = threadIdx.x >> 6;
  const int lane = threadIdx.x & 63;
  const int wid  = blockIdx.x * 4 + wv;
  const int qt   = wid >> 3;          // 0..255
  const int h    = wid & 7;
  const int r0   = qt * 16;
  const int lo16 = lane & 15;
  const int quad = lane >> 4;
  __hip_bfloat16 (*Plds)[40] = Plds_all[wv];

  // batches of this lane's 4 C-layout rows
  int rb[4];
  #pragma unroll
  for (int r = 0; r < 4; r++) rb[r] = bidx[r0 + quad * 4 + r];

  const int kstart = segs[bidx[r0]] & ~31;
  const int kend   = segs[16 + bidx[r0 + 15]];

  // Q A-frag: row = r0+lo16, k = quad*8..+7 (contiguous 16B)
  const short8 qf = *(const short8*)(Qb + ((size_t)h * NROWS + r0 + lo16) * HD + quad * 8);

  f32x4 o0 = {0.f, 0.f, 0.f, 0.f}, o1 = {0.f, 0.f, 0.f, 0.f};
  float m[4], l[4];
  #pragma unroll
  for (int r = 0; r < 4; r++) { m[r] = -1e30f; l[r] = 0.0f; }

  const float scale = 0.17677669529663687f;  // 1/sqrt(32)

  for (int c0 = kstart; c0 < kend; c0 += 32) {
    // ---- K B-frags (cols c0..c0+15, c0+16..c0+31) ----
    const int col0 = c0 + lo16;
    const int col1 = col0 + 16;
    const int colc0 = min(col0, NROWS - 1);
    const int colc1 = min(col1, NROWS - 1);
    const short8 kf0 = *(const short8*)(Kb + ((size_t)h * NROWS + colc0) * HD + quad * 8);
    const short8 kf1 = *(const short8*)(Kb + ((size_t)h * NROWS + colc1) * HD + quad * 8);
    // ---- V B-frags: B[k=col][n=d] = Vt[d][col] (contiguous 16B along col) ----
    const int vc = min(c0 + quad * 8, NROWS - 8);
    const short8 vf0 = *(const short8*)(Vt + ((size_t)h * HD + lo16) * NROWS + vc);
    const short8 vf1 = *(const short8*)(Vt + ((size_t)h * HD + 16 + lo16) * NROWS + vc);
    // ---- column batches for mask ----
    const int cb0 = bidx[colc0];
    const int cb1 = bidx[colc1];

    f32x4 z = {0.f, 0.f, 0.f, 0.f};
    f32x4 s0 = __builtin_amdgcn_mfma_f32_16x16x32_bf16(qf, kf0, z, 0, 0, 0);
    f32x4 s1 = __builtin_amdgcn_mfma_f32_16x16x32_bf16(qf, kf1, z, 0, 0, 0);

    float p0[4], p1[4];
    #pragma unroll
    for (int r = 0; r < 4; r++) {
      const bool ok0 = (col0 < NROWS) && (cb0 == rb[r]);
      const bool ok1 = (col1 < NROWS) && (cb1 == rb[r]);
      const float sc0 = ok0 ? s0[r] * scale : -1e30f;
      const float sc1 = ok1 ? s1[r] * scale : -1e30f;
      float mx = fmaxf(sc0, sc1);
      mx = fmaxf(mx, __shfl_xor(mx, 1));
      mx = fmaxf(mx, __shfl_xor(mx, 2));
      mx = fmaxf(mx, __shfl_xor(mx, 4));
      mx = fmaxf(mx, __shfl_xor(mx, 8));
      const float nm = fmaxf(m[r], mx);
      const float alpha = __expf(m[r] - nm);
      p0[r] = ok0 ? __expf(sc0 - nm) : 0.0f;
      p1[r] = ok1 ? __expf(sc1 - nm) : 0.0f;
      float ps = p0[r] + p1[r];
      ps += __shfl_xor(ps, 1);
      ps += __shfl_xor(ps, 2);
      ps += __shfl_xor(ps, 4);
      ps += __shfl_xor(ps, 8);
      l[r] = l[r] * alpha + ps;
      m[r] = nm;
      o0[r] *= alpha;
      o1[r] *= alpha;
    }

    // ---- P: C-layout -> LDS -> A-layout ----
    #pragma unroll
    for (int r = 0; r < 4; r++) {
      Plds[quad * 4 + r][lo16]      = __float2bfloat16(p0[r]);
      Plds[quad * 4 + r][lo16 + 16] = __float2bfloat16(p1[r]);
    }
    const short8 pf = *(const short8*)&Plds[lo16][quad * 8];

    o0 = __builtin_amdgcn_mfma_f32_16x16x32_bf16(pf, vf0, o0, 0, 0, 0);
    o1 = __builtin_amdgcn_mfma_f32_16x16x32_bf16(pf, vf1, o1, 0, 0, 0);
  }

  // ---- epilogue: normalize, write [N][256] fp32 ----
  #pragma unroll
  for (int r = 0; r < 4; r++) {
    const float inv = 1.0f / l[r];
    const int row = r0 + quad * 4 + r;
    out[(size_t)row * DMODEL + h * HD + lo16]      = o0[r] * inv;
    out[(size_t)row * DMODEL + h * HD + 16 + lo16] = o1[r] * inv;
  }
}

// ---------------- Residual + LayerNorm, one block (256 thr) per row --------
__global__ __launch_bounds__(256) void ln_kernel(
    const float* __restrict__ x, const float* __restrict__ delta,
    const float* __restrict__ gamma, const float* __restrict__ beta,
    float* __restrict__ out) {
  const int n = blockIdx.x;
  const int t = threadIdx.x;
  __shared__ float red[8];
  const float v = x[(size_t)n * DMODEL + t] + delta[(size_t)n * DMODEL + t];
  float s = v;
  #pragma unroll
  for (int off = 32; off; off >>= 1) s += __shfl_xor(s, off);
  const int w = t >> 6;
  if ((t & 63) == 0) red[w] = s;
  __syncthreads();
  const float mean = (red[0] + red[1] + red[2] + red[3]) * (1.0f / DMODEL);
  const float d0 = v - mean;
  float s2 = d0 * d0;
  #pragma unroll
  for (int off = 32; off; off >>= 1) s2 += __shfl_xor(s2, off);
  if ((t & 63) == 0) red[4 + w] = s2;
  __syncthreads();
  const float var = (red[4] + red[5] + red[6] + red[7]) * (1.0f / DMODEL);
  out[(size_t)n * DMODEL + t] = d0 * rsqrtf(var + 1e-5f) * gamma[t] + beta[t];
}

extern "C" void kernel_launch(void* const* d_in, const int* in_sizes, int n_in,
                              void* d_out, int out_size, void* d_ws, size_t ws_size,
                              hipStream_t stream) {
  const float* slots  = (const float*)d_in[0];  // [1, N, D]
  const int*   bidx   = (const int*)  d_in[1];  // [N]
  const float* w_in   = (const float*)d_in[2];  // [768, 256]
  const float* b_in   = (const float*)d_in[3];  // [768]
  const float* w_out  = (const float*)d_in[4];  // [256, 256]
  const float* b_out  = (const float*)d_in[5];  // [256]
  const float* ln_g   = (const float*)d_in[6];  // [256]
  const float* ln_b   = (const float*)d_in[7];  // [256]
  float* out = (float*)d_out;

  char* ws = (char*)d_ws;
  __hip_bfloat16* Qb = (__hip_bfloat16*)(ws);                    // 2 MB
  __hip_bfloat16* Kb = (__hip_bfloat16*)(ws + (2u << 20));       // 2 MB
  __hip_bfloat16* Vt = (__hip_bfloat16*)(ws + (4u << 20));       // 2 MB [H][32][N]
  float* attn = (float*)(ws + (6u << 20));                       // 4 MB [N][256]
  float* proj = (float*)(ws + (10u << 20));                      // 4 MB [N][256]
  int*   segs = (int*)(ws + (14u << 20));                        // 32 ints

  // 0) segment bounds from sorted batch_idx
  seg_kernel<<<NROWS / 256, 256, 0, stream>>>(bidx, segs);
  // 1) QKV projection (fp32 VALU GEMM) with bf16 scatter epilogue
  {
    dim3 grid(768 / BN, NROWS / BM);
    gemm_bt<true><<<grid, 256, 0, stream>>>(slots, w_in, b_in, nullptr,
                                            Qb, Kb, Vt, DMODEL, 768);
  }
  // 2) block-diagonal MFMA flash attention
  attn_mfma<<<(NROWS / 16) * NHEADS / 4, 256, 0, stream>>>(Qb, Kb, Vt, bidx,
                                                           segs, attn);
  // 3) output projection (fp32 VALU GEMM)
  {
    dim3 grid(DMODEL / BN, NROWS / BM);
    gemm_bt<false><<<grid, 256, 0, stream>>>(attn, w_out, b_out, proj,
                                             nullptr, nullptr, nullptr,
                                             DMODEL, DMODEL);
  }
  // 4) residual + layernorm
  ln_kernel<<<NROWS, 256, 0, stream>>>(slots, proj, ln_g, ln_b, out);
}

// Round 3
// 131.407 us; speedup vs baseline: 2.9554x; 1.1077x over previous
//
#include <hip/hip_runtime.h>
#include <hip/hip_bf16.h>

#define NROWS 4096
#define DMODEL 256
#define NHEADS 8
#define HD 32

typedef __attribute__((ext_vector_type(8))) short short8;
typedef __attribute__((ext_vector_type(4))) float f32x4;

// ---------------- fp32 -> bf16 cast (grid-stride by 4) ---------------------
__global__ __launch_bounds__(256) void cast_bf16_kernel(
    const float* __restrict__ src, __hip_bfloat16* __restrict__ dst, int n) {
  const int i = (blockIdx.x * 256 + threadIdx.x) * 4;
  if (i >= n) return;
  const float4 v = *(const float4*)(src + i);
  __hip_bfloat162 lo, hi;
  lo.x = __float2bfloat16(v.x); lo.y = __float2bfloat16(v.y);
  hi.x = __float2bfloat16(v.z); hi.y = __float2bfloat16(v.w);
  *(__hip_bfloat162*)(dst + i) = lo;
  *(__hip_bfloat162*)(dst + i + 2) = hi;
}

// ---------------- MFMA GEMM: C[M x Nd] = A @ B^T + bias --------------------
// A[M][K] bf16, B[Nd][K] bf16. 128x128 tile, BK=32, 256 thr = 4 waves,
// each wave computes a 64x64 quadrant as 4x4 mfma_f32_16x16x32_bf16.
// Staging: global_load_lds width=16, contiguous LDS (lane order == layout).
__device__ __forceinline__ void load_lds16(const void* g, void* l) {
  __builtin_amdgcn_global_load_lds(
      (const __attribute__((address_space(1))) unsigned int*)g,
      (__attribute__((address_space(3))) unsigned int*)l, 16, 0, 0);
}

template<bool SCATTER>
__global__ __launch_bounds__(256) void gemm_mfma(
    const __hip_bfloat16* __restrict__ A, const __hip_bfloat16* __restrict__ B,
    const float* __restrict__ bias, float* __restrict__ C,
    __hip_bfloat16* __restrict__ Qo, __hip_bfloat16* __restrict__ Ko,
    __hip_bfloat16* __restrict__ Vo,   // Vo TRANSPOSED: [H][HD][N]
    int Nd, int K) {
  __shared__ __hip_bfloat16 As[128][32];  // 8 KB, rows of 64 B
  __shared__ __hip_bfloat16 Bs[128][32];  // 8 KB
  const int tid  = threadIdx.x;
  const int w    = tid >> 6;
  const int lane = tid & 63;
  const int lo16 = lane & 15;
  const int quad = lane >> 4;
  const int bm = blockIdx.y * 128;
  const int bn = blockIdx.x * 128;
  const int wm = (w & 1) * 64;
  const int wn = (w >> 1) * 64;

  f32x4 acc[4][4] = {};

  // staging: wave w covers bytes [w*2048, w*2048+2048) of each 8192 B tile,
  // as two 1024 B instructions (lane dest = uniform base + lane*16).
  const int fbase = w * 2048;

  for (int k0 = 0; k0 < K; k0 += 32) {
    #pragma unroll
    for (int inst = 0; inst < 2; inst++) {
      const int f   = fbase + inst * 1024 + lane * 16;  // byte offset in tile
      const int row = f >> 6;                            // 64 B per row
      const int kb  = (f & 63) >> 1;                     // bf16 offset in row
      load_lds16(A + (size_t)(bm + row) * K + k0 + kb,
                 (char*)&As[0][0] + fbase + inst * 1024);
      load_lds16(B + (size_t)(bn + row) * K + k0 + kb,
                 (char*)&Bs[0][0] + fbase + inst * 1024);
    }
    __syncthreads();
    short8 af[4], bf[4];
    #pragma unroll
    for (int i = 0; i < 4; i++) {
      af[i] = *(const short8*)&As[wm + i * 16 + lo16][quad * 8];
      bf[i] = *(const short8*)&Bs[wn + i * 16 + lo16][quad * 8];
    }
    #pragma unroll
    for (int mi = 0; mi < 4; mi++)
      #pragma unroll
      for (int ni = 0; ni < 4; ni++)
        acc[mi][ni] = __builtin_amdgcn_mfma_f32_16x16x32_bf16(
            af[mi], bf[ni], acc[mi][ni], 0, 0, 0);
    __syncthreads();
  }

  // epilogue: C/D layout col=lane&15, row=quad*4+reg
  #pragma unroll
  for (int mi = 0; mi < 4; mi++) {
    const int rbase = bm + wm + mi * 16 + quad * 4;
    #pragma unroll
    for (int ni = 0; ni < 4; ni++) {
      const int col = bn + wn + ni * 16 + lo16;
      const float bv = bias[col];
      #pragma unroll
      for (int r = 0; r < 4; r++) {
        const int n = rbase + r;
        const float v = acc[mi][ni][r] + bv;
        if (SCATTER) {
          const int sel = col >> 8;        // 0:Q 1:K 2:V
          const int h = (col & 255) >> 5;
          const int d = col & 31;
          const __hip_bfloat16 bv16 = __float2bfloat16(v);
          if (sel == 0)      Qo[((size_t)h * NROWS + n) * HD + d] = bv16;
          else if (sel == 1) Ko[((size_t)h * NROWS + n) * HD + d] = bv16;
          else               Vo[((size_t)h * HD + d) * NROWS + n] = bv16;
        } else {
          C[(size_t)n * Nd + col] = v;
        }
      }
    }
  }
}

// ---------------- segment bounds: seg[b] = start, seg[16+b] = end ---------
__global__ void seg_kernel(const int* __restrict__ bidx, int* __restrict__ segs) {
  const int r = blockIdx.x * 256 + threadIdx.x;
  if (r >= NROWS) return;
  const int b = bidx[r];
  if (r == 0 || bidx[r - 1] != b) segs[b] = r;
  if (r == NROWS - 1 || bidx[r + 1] != b) segs[16 + b] = r + 1;
}

// ---------------- MFMA flash attention (writes bf16) -----------------------
__global__ __launch_bounds__(256) void attn_mfma(
    const __hip_bfloat16* __restrict__ Qb,  // [H][N][32]
    const __hip_bfloat16* __restrict__ Kb,  // [H][N][32]
    const __hip_bfloat16* __restrict__ Vt,  // [H][32][N]
    const int* __restrict__ bidx,
    const int* __restrict__ segs,
    __hip_bfloat16* __restrict__ out)       // [N][256] bf16
{
  __shared__ __align__(16) __hip_bfloat16 Plds_all[4][16][40];  // pad 32->40
  const int wv   = threadIdx.x >> 6;
  const int lane = threadIdx.x & 63;
  const int wid  = blockIdx.x * 4 + wv;
  const int qt   = wid >> 3;          // 0..255
  const int h    = wid & 7;
  const int r0   = qt * 16;
  const int lo16 = lane & 15;
  const int quad = lane >> 4;
  __hip_bfloat16 (*Plds)[40] = Plds_all[wv];

  int rb[4];
  #pragma unroll
  for (int r = 0; r < 4; r++) rb[r] = bidx[r0 + quad * 4 + r];

  const int kstart = segs[bidx[r0]] & ~31;
  const int kend   = segs[16 + bidx[r0 + 15]];

  const short8 qf = *(const short8*)(Qb + ((size_t)h * NROWS + r0 + lo16) * HD + quad * 8);

  f32x4 o0 = {0.f, 0.f, 0.f, 0.f}, o1 = {0.f, 0.f, 0.f, 0.f};
  float m[4], l[4];
  #pragma unroll
  for (int r = 0; r < 4; r++) { m[r] = -1e30f; l[r] = 0.0f; }

  const float scale = 0.17677669529663687f;  // 1/sqrt(32)

  for (int c0 = kstart; c0 < kend; c0 += 32) {
    const int col0 = c0 + lo16;
    const int col1 = col0 + 16;
    const int colc0 = min(col0, NROWS - 1);
    const int colc1 = min(col1, NROWS - 1);
    const short8 kf0 = *(const short8*)(Kb + ((size_t)h * NROWS + colc0) * HD + quad * 8);
    const short8 kf1 = *(const short8*)(Kb + ((size_t)h * NROWS + colc1) * HD + quad * 8);
    const int vc = min(c0 + quad * 8, NROWS - 8);
    const short8 vf0 = *(const short8*)(Vt + ((size_t)h * HD + lo16) * NROWS + vc);
    const short8 vf1 = *(const short8*)(Vt + ((size_t)h * HD + 16 + lo16) * NROWS + vc);
    const int cb0 = bidx[colc0];
    const int cb1 = bidx[colc1];

    f32x4 z = {0.f, 0.f, 0.f, 0.f};
    f32x4 s0 = __builtin_amdgcn_mfma_f32_16x16x32_bf16(qf, kf0, z, 0, 0, 0);
    f32x4 s1 = __builtin_amdgcn_mfma_f32_16x16x32_bf16(qf, kf1, z, 0, 0, 0);

    float p0[4], p1[4];
    #pragma unroll
    for (int r = 0; r < 4; r++) {
      const bool ok0 = (col0 < NROWS) && (cb0 == rb[r]);
      const bool ok1 = (col1 < NROWS) && (cb1 == rb[r]);
      const float sc0 = ok0 ? s0[r] * scale : -1e30f;
      const float sc1 = ok1 ? s1[r] * scale : -1e30f;
      float mx = fmaxf(sc0, sc1);
      mx = fmaxf(mx, __shfl_xor(mx, 1));
      mx = fmaxf(mx, __shfl_xor(mx, 2));
      mx = fmaxf(mx, __shfl_xor(mx, 4));
      mx = fmaxf(mx, __shfl_xor(mx, 8));
      const float nm = fmaxf(m[r], mx);
      const float alpha = __expf(m[r] - nm);
      p0[r] = ok0 ? __expf(sc0 - nm) : 0.0f;
      p1[r] = ok1 ? __expf(sc1 - nm) : 0.0f;
      float ps = p0[r] + p1[r];
      ps += __shfl_xor(ps, 1);
      ps += __shfl_xor(ps, 2);
      ps += __shfl_xor(ps, 4);
      ps += __shfl_xor(ps, 8);
      l[r] = l[r] * alpha + ps;
      m[r] = nm;
      o0[r] *= alpha;
      o1[r] *= alpha;
    }

    #pragma unroll
    for (int r = 0; r < 4; r++) {
      Plds[quad * 4 + r][lo16]      = __float2bfloat16(p0[r]);
      Plds[quad * 4 + r][lo16 + 16] = __float2bfloat16(p1[r]);
    }
    const short8 pf = *(const short8*)&Plds[lo16][quad * 8];

    o0 = __builtin_amdgcn_mfma_f32_16x16x32_bf16(pf, vf0, o0, 0, 0, 0);
    o1 = __builtin_amdgcn_mfma_f32_16x16x32_bf16(pf, vf1, o1, 0, 0, 0);
  }

  #pragma unroll
  for (int r = 0; r < 4; r++) {
    const float inv = 1.0f / l[r];
    const int row = r0 + quad * 4 + r;
    out[(size_t)row * DMODEL + h * HD + lo16]      = __float2bfloat16(o0[r] * inv);
    out[(size_t)row * DMODEL + h * HD + 16 + lo16] = __float2bfloat16(o1[r] * inv);
  }
}

// ---------------- Residual + LayerNorm, one block (256 thr) per row --------
__global__ __launch_bounds__(256) void ln_kernel(
    const float* __restrict__ x, const float* __restrict__ delta,
    const float* __restrict__ gamma, const float* __restrict__ beta,
    float* __restrict__ out) {
  const int n = blockIdx.x;
  const int t = threadIdx.x;
  __shared__ float red[8];
  const float v = x[(size_t)n * DMODEL + t] + delta[(size_t)n * DMODEL + t];
  float s = v;
  #pragma unroll
  for (int off = 32; off; off >>= 1) s += __shfl_xor(s, off);
  const int w = t >> 6;
  if ((t & 63) == 0) red[w] = s;
  __syncthreads();
  const float mean = (red[0] + red[1] + red[2] + red[3]) * (1.0f / DMODEL);
  const float d0 = v - mean;
  float s2 = d0 * d0;
  #pragma unroll
  for (int off = 32; off; off >>= 1) s2 += __shfl_xor(s2, off);
  if ((t & 63) == 0) red[4 + w] = s2;
  __syncthreads();
  const float var = (red[4] + red[5] + red[6] + red[7]) * (1.0f / DMODEL);
  out[(size_t)n * DMODEL + t] = d0 * rsqrtf(var + 1e-5f) * gamma[t] + beta[t];
}

extern "C" void kernel_launch(void* const* d_in, const int* in_sizes, int n_in,
                              void* d_out, int out_size, void* d_ws, size_t ws_size,
                              hipStream_t stream) {
  const float* slots  = (const float*)d_in[0];  // [1, N, D]
  const int*   bidx   = (const int*)  d_in[1];  // [N]
  const float* w_in   = (const float*)d_in[2];  // [768, 256]
  const float* b_in   = (const float*)d_in[3];  // [768]
  const float* w_out  = (const float*)d_in[4];  // [256, 256]
  const float* b_out  = (const float*)d_in[5];  // [256]
  const float* ln_g   = (const float*)d_in[6];  // [256]
  const float* ln_b   = (const float*)d_in[7];  // [256]
  float* out = (float*)d_out;

  char* ws = (char*)d_ws;
  __hip_bfloat16* Abf   = (__hip_bfloat16*)(ws);                 // 2 MB slots bf16
  __hip_bfloat16* Qb    = (__hip_bfloat16*)(ws + (2u  << 20));   // 2 MB
  __hip_bfloat16* Kb    = (__hip_bfloat16*)(ws + (4u  << 20));   // 2 MB
  __hip_bfloat16* Vt    = (__hip_bfloat16*)(ws + (6u  << 20));   // 2 MB [H][32][N]
  __hip_bfloat16* attnb = (__hip_bfloat16*)(ws + (8u  << 20));   // 2 MB [N][256] bf16
  float*          proj  = (float*)         (ws + (10u << 20));   // 4 MB fp32
  __hip_bfloat16* Winb  = (__hip_bfloat16*)(ws + (14u << 20));   // 384 KB
  __hip_bfloat16* Woutb = (__hip_bfloat16*)(ws + (14u << 20) + (512u << 10)); // 128 KB
  int*            segs  = (int*)           (ws + (15u << 20));   // 32 ints

  // 0) casts + segment bounds
  cast_bf16_kernel<<<1024, 256, 0, stream>>>(slots, Abf, NROWS * DMODEL);
  cast_bf16_kernel<<<192, 256, 0, stream>>>(w_in, Winb, 768 * DMODEL);
  cast_bf16_kernel<<<64, 256, 0, stream>>>(w_out, Woutb, DMODEL * DMODEL);
  seg_kernel<<<NROWS / 256, 256, 0, stream>>>(bidx, segs);

  // 1) QKV projection (bf16 MFMA) with scatter epilogue
  {
    dim3 grid(768 / 128, NROWS / 128);
    gemm_mfma<true><<<grid, 256, 0, stream>>>(Abf, Winb, b_in, nullptr,
                                              Qb, Kb, Vt, 768, DMODEL);
  }
  // 2) block-diagonal MFMA flash attention -> bf16
  attn_mfma<<<(NROWS / 16) * NHEADS / 4, 256, 0, stream>>>(Qb, Kb, Vt, bidx,
                                                           segs, attnb);
  // 3) output projection (bf16 MFMA) -> fp32
  {
    dim3 grid(DMODEL / 128, NROWS / 128);
    gemm_mfma<false><<<grid, 256, 0, stream>>>(attnb, Woutb, b_out, proj,
                                               nullptr, nullptr, nullptr,
                                               DMODEL, DMODEL);
  }
  // 4) residual + layernorm
  ln_kernel<<<NROWS, 256, 0, stream>>>(slots, proj, ln_g, ln_b, out);
}

// Round 4
// 120.795 us; speedup vs baseline: 3.2150x; 1.0878x over previous
//
#include <hip/hip_runtime.h>
#include <hip/hip_bf16.h>

#define NROWS 4096
#define DMODEL 256
#define NHEADS 8
#define HD 32

typedef __attribute__((ext_vector_type(8))) short short8;
typedef __attribute__((ext_vector_type(4))) float f32x4;

// ---------------- prep: casts (fp32->bf16) + segment bounds ----------------
// blocks [0,1024): slots (1M el); [1024,1216): w_in (192K el);
// [1216,1280): w_out (64K el); [1280,1296): seg scan.
__global__ __launch_bounds__(256) void prep_kernel(
    const float* __restrict__ slots, const float* __restrict__ w_in,
    const float* __restrict__ w_out, const int* __restrict__ bidx,
    __hip_bfloat16* __restrict__ Abf, __hip_bfloat16* __restrict__ Winb,
    __hip_bfloat16* __restrict__ Woutb, int* __restrict__ segs) {
  const int bid = blockIdx.x;
  const float* src;
  __hip_bfloat16* dst;
  int i;
  if (bid < 1024)      { src = slots; dst = Abf;   i = (bid * 256 + (int)threadIdx.x) * 4; }
  else if (bid < 1216) { src = w_in;  dst = Winb;  i = ((bid - 1024) * 256 + (int)threadIdx.x) * 4; }
  else if (bid < 1280) { src = w_out; dst = Woutb; i = ((bid - 1216) * 256 + (int)threadIdx.x) * 4; }
  else {
    const int r = (bid - 1280) * 256 + threadIdx.x;
    const int b = bidx[r];
    if (r == 0 || bidx[r - 1] != b) segs[b] = r;
    if (r == NROWS - 1 || bidx[r + 1] != b) segs[16 + b] = r + 1;
    return;
  }
  const float4 v = *(const float4*)(src + i);
  __hip_bfloat162 lo, hi;
  lo.x = __float2bfloat16(v.x); lo.y = __float2bfloat16(v.y);
  hi.x = __float2bfloat16(v.z); hi.y = __float2bfloat16(v.w);
  *(__hip_bfloat162*)(dst + i) = lo;
  *(__hip_bfloat162*)(dst + i + 2) = hi;
}

// ---------------- MFMA GEMM: C[M x Nd] = A @ B^T + bias --------------------
__device__ __forceinline__ void load_lds16(const void* g, void* l) {
  __builtin_amdgcn_global_load_lds(
      (const __attribute__((address_space(1))) unsigned int*)g,
      (__attribute__((address_space(3))) unsigned int*)l, 16, 0, 0);
}

template<bool SCATTER>
__global__ __launch_bounds__(256) void gemm_mfma(
    const __hip_bfloat16* __restrict__ A, const __hip_bfloat16* __restrict__ B,
    const float* __restrict__ bias, float* __restrict__ C,
    __hip_bfloat16* __restrict__ Qo, __hip_bfloat16* __restrict__ Ko,
    __hip_bfloat16* __restrict__ Vo,   // Vo TRANSPOSED: [H][HD][N]
    int Nd, int K) {
  __shared__ __hip_bfloat16 As[128][32];
  __shared__ __hip_bfloat16 Bs[128][32];
  const int tid  = threadIdx.x;
  const int w    = tid >> 6;
  const int lane = tid & 63;
  const int lo16 = lane & 15;
  const int quad = lane >> 4;
  const int bm = blockIdx.y * 128;
  const int bn = blockIdx.x * 128;
  const int wm = (w & 1) * 64;
  const int wn = (w >> 1) * 64;

  f32x4 acc[4][4] = {};
  const int fbase = w * 2048;

  for (int k0 = 0; k0 < K; k0 += 32) {
    #pragma unroll
    for (int inst = 0; inst < 2; inst++) {
      const int f   = fbase + inst * 1024 + lane * 16;
      const int row = f >> 6;
      const int kb  = (f & 63) >> 1;
      load_lds16(A + (size_t)(bm + row) * K + k0 + kb,
                 (char*)&As[0][0] + fbase + inst * 1024);
      load_lds16(B + (size_t)(bn + row) * K + k0 + kb,
                 (char*)&Bs[0][0] + fbase + inst * 1024);
    }
    __syncthreads();
    short8 af[4], bf[4];
    #pragma unroll
    for (int i = 0; i < 4; i++) {
      af[i] = *(const short8*)&As[wm + i * 16 + lo16][quad * 8];
      bf[i] = *(const short8*)&Bs[wn + i * 16 + lo16][quad * 8];
    }
    #pragma unroll
    for (int mi = 0; mi < 4; mi++)
      #pragma unroll
      for (int ni = 0; ni < 4; ni++)
        acc[mi][ni] = __builtin_amdgcn_mfma_f32_16x16x32_bf16(
            af[mi], bf[ni], acc[mi][ni], 0, 0, 0);
    __syncthreads();
  }

  #pragma unroll
  for (int mi = 0; mi < 4; mi++) {
    const int rbase = bm + wm + mi * 16 + quad * 4;
    #pragma unroll
    for (int ni = 0; ni < 4; ni++) {
      const int col = bn + wn + ni * 16 + lo16;
      const float bv = bias[col];
      #pragma unroll
      for (int r = 0; r < 4; r++) {
        const int n = rbase + r;
        const float v = acc[mi][ni][r] + bv;
        if (SCATTER) {
          const int sel = col >> 8;        // 0:Q 1:K 2:V
          const int h = (col & 255) >> 5;
          const int d = col & 31;
          const __hip_bfloat16 bv16 = __float2bfloat16(v);
          if (sel == 0)      Qo[((size_t)h * NROWS + n) * HD + d] = bv16;
          else if (sel == 1) Ko[((size_t)h * NROWS + n) * HD + d] = bv16;
          else               Vo[((size_t)h * HD + d) * NROWS + n] = bv16;
        } else {
          C[(size_t)n * Nd + col] = v;
        }
      }
    }
  }
}

// ---------------- MFMA flash attention, 128-col k-tiles --------------------
// One wave per (16-row q-tile, head). Mask via per-row segment bounds
// (batch_idx sorted => col in [st[r], en[r])). Softmax reduction once per
// 128 cols: per-lane max/sum over 8 locals, then 4-shfl tree over 16 lanes.
__global__ __launch_bounds__(256, 2) void attn_mfma(
    const __hip_bfloat16* __restrict__ Qb,  // [H][N][32]
    const __hip_bfloat16* __restrict__ Kb,  // [H][N][32]
    const __hip_bfloat16* __restrict__ Vt,  // [H][32][N]
    const int* __restrict__ bidx,
    const int* __restrict__ segs,
    __hip_bfloat16* __restrict__ out)       // [N][256] bf16
{
  __shared__ __align__(16) __hip_bfloat16 Plds_all[4][16][136];  // pad 128->136
  const int wv   = threadIdx.x >> 6;
  const int lane = threadIdx.x & 63;
  const int wid  = blockIdx.x * 4 + wv;
  const int qt   = wid >> 3;
  const int h    = wid & 7;
  const int r0   = qt * 16;
  const int lo16 = lane & 15;
  const int quad = lane >> 4;
  __hip_bfloat16 (*Plds)[136] = Plds_all[wv];

  // per-row segment bounds (mask: col in [st, en))
  int st[4], en[4];
  #pragma unroll
  for (int r = 0; r < 4; r++) {
    const int b = bidx[r0 + quad * 4 + r];
    st[r] = segs[b];
    en[r] = segs[16 + b];
  }

  const int kstart = segs[bidx[r0]] & ~31;
  const int kend   = segs[16 + bidx[r0 + 15]];

  const short8 qf = *(const short8*)(Qb + ((size_t)h * NROWS + r0 + lo16) * HD + quad * 8);

  f32x4 o0 = {0.f, 0.f, 0.f, 0.f}, o1 = {0.f, 0.f, 0.f, 0.f};
  float m[4], l[4];
  #pragma unroll
  for (int r = 0; r < 4; r++) { m[r] = -1e30f; l[r] = 0.0f; }

  const float scale = 0.17677669529663687f;  // 1/sqrt(32)

  for (int c0 = kstart; c0 < kend; c0 += 128) {
    // ---- K B-frags: 8 sub-tiles of 16 cols ----
    short8 kf[8];
    #pragma unroll
    for (int j = 0; j < 8; j++) {
      const int cc = min(c0 + j * 16 + lo16, NROWS - 1);
      kf[j] = *(const short8*)(Kb + ((size_t)h * NROWS + cc) * HD + quad * 8);
    }
    // ---- V B-frags: per 32-col group, n in {lo16, 16+lo16} ----
    short8 vf[8];
    #pragma unroll
    for (int t = 0; t < 4; t++) {
      const int vc = min(c0 + t * 32 + quad * 8, NROWS - 8);
      vf[2 * t]     = *(const short8*)(Vt + ((size_t)h * HD + lo16) * NROWS + vc);
      vf[2 * t + 1] = *(const short8*)(Vt + ((size_t)h * HD + 16 + lo16) * NROWS + vc);
    }
    // ---- QK^T: 8 MFMAs ----
    f32x4 s[8];
    const f32x4 z = {0.f, 0.f, 0.f, 0.f};
    #pragma unroll
    for (int j = 0; j < 8; j++)
      s[j] = __builtin_amdgcn_mfma_f32_16x16x32_bf16(qf, kf[j], z, 0, 0, 0);

    // ---- masked online softmax, one reduction pass per 128 cols ----
    #pragma unroll
    for (int r = 0; r < 4; r++) {
      float sc[8];
      #pragma unroll
      for (int j = 0; j < 8; j++) {
        const int col = c0 + j * 16 + lo16;
        const bool ok = (col >= st[r]) & (col < en[r]);
        sc[j] = ok ? s[j][r] * scale : -1e30f;
      }
      float mx = sc[0];
      #pragma unroll
      for (int j = 1; j < 8; j++) mx = fmaxf(mx, sc[j]);
      mx = fmaxf(mx, __shfl_xor(mx, 1));
      mx = fmaxf(mx, __shfl_xor(mx, 2));
      mx = fmaxf(mx, __shfl_xor(mx, 4));
      mx = fmaxf(mx, __shfl_xor(mx, 8));
      const float nm = fmaxf(m[r], mx);
      const float alpha = __expf(m[r] - nm);
      float ps = 0.0f;
      #pragma unroll
      for (int j = 0; j < 8; j++) {
        const float p = (sc[j] > -5e29f) ? __expf(sc[j] - nm) : 0.0f;
        ps += p;
        Plds[quad * 4 + r][lo16 + j * 16] = __float2bfloat16(p);
      }
      ps += __shfl_xor(ps, 1);
      ps += __shfl_xor(ps, 2);
      ps += __shfl_xor(ps, 4);
      ps += __shfl_xor(ps, 8);
      l[r] = l[r] * alpha + ps;
      m[r] = nm;
      o0[r] *= alpha;
      o1[r] *= alpha;
    }

    // ---- P (A-layout from LDS) @ V: 8 MFMAs ----
    #pragma unroll
    for (int t = 0; t < 4; t++) {
      const short8 pf = *(const short8*)&Plds[lo16][t * 32 + quad * 8];
      o0 = __builtin_amdgcn_mfma_f32_16x16x32_bf16(pf, vf[2 * t],     o0, 0, 0, 0);
      o1 = __builtin_amdgcn_mfma_f32_16x16x32_bf16(pf, vf[2 * t + 1], o1, 0, 0, 0);
    }
  }

  #pragma unroll
  for (int r = 0; r < 4; r++) {
    const float inv = 1.0f / l[r];
    const int row = r0 + quad * 4 + r;
    out[(size_t)row * DMODEL + h * HD + lo16]      = __float2bfloat16(o0[r] * inv);
    out[(size_t)row * DMODEL + h * HD + 16 + lo16] = __float2bfloat16(o1[r] * inv);
  }
}

// ---------------- Residual + LayerNorm, one block (256 thr) per row --------
__global__ __launch_bounds__(256) void ln_kernel(
    const float* __restrict__ x, const float* __restrict__ delta,
    const float* __restrict__ gamma, const float* __restrict__ beta,
    float* __restrict__ out) {
  const int n = blockIdx.x;
  const int t = threadIdx.x;
  __shared__ float red[8];
  const float v = x[(size_t)n * DMODEL + t] + delta[(size_t)n * DMODEL + t];
  float s = v;
  #pragma unroll
  for (int off = 32; off; off >>= 1) s += __shfl_xor(s, off);
  const int w = t >> 6;
  if ((t & 63) == 0) red[w] = s;
  __syncthreads();
  const float mean = (red[0] + red[1] + red[2] + red[3]) * (1.0f / DMODEL);
  const float d0 = v - mean;
  float s2 = d0 * d0;
  #pragma unroll
  for (int off = 32; off; off >>= 1) s2 += __shfl_xor(s2, off);
  if ((t & 63) == 0) red[4 + w] = s2;
  __syncthreads();
  const float var = (red[4] + red[5] + red[6] + red[7]) * (1.0f / DMODEL);
  out[(size_t)n * DMODEL + t] = d0 * rsqrtf(var + 1e-5f) * gamma[t] + beta[t];
}

extern "C" void kernel_launch(void* const* d_in, const int* in_sizes, int n_in,
                              void* d_out, int out_size, void* d_ws, size_t ws_size,
                              hipStream_t stream) {
  const float* slots  = (const float*)d_in[0];
  const int*   bidx   = (const int*)  d_in[1];
  const float* w_in   = (const float*)d_in[2];
  const float* b_in   = (const float*)d_in[3];
  const float* w_out  = (const float*)d_in[4];
  const float* b_out  = (const float*)d_in[5];
  const float* ln_g   = (const float*)d_in[6];
  const float* ln_b   = (const float*)d_in[7];
  float* out = (float*)d_out;

  char* ws = (char*)d_ws;
  __hip_bfloat16* Abf   = (__hip_bfloat16*)(ws);                 // 2 MB slots bf16
  __hip_bfloat16* Qb    = (__hip_bfloat16*)(ws + (2u  << 20));   // 2 MB
  __hip_bfloat16* Kb    = (__hip_bfloat16*)(ws + (4u  << 20));   // 2 MB
  __hip_bfloat16* Vt    = (__hip_bfloat16*)(ws + (6u  << 20));   // 2 MB [H][32][N]
  __hip_bfloat16* attnb = (__hip_bfloat16*)(ws + (8u  << 20));   // 2 MB [N][256] bf16
  float*          proj  = (float*)         (ws + (10u << 20));   // 4 MB fp32
  __hip_bfloat16* Winb  = (__hip_bfloat16*)(ws + (14u << 20));   // 384 KB
  __hip_bfloat16* Woutb = (__hip_bfloat16*)(ws + (14u << 20) + (512u << 10)); // 128 KB
  int*            segs  = (int*)           (ws + (15u << 20));   // 32 ints

  // 0) fused casts + segment bounds
  prep_kernel<<<1296, 256, 0, stream>>>(slots, w_in, w_out, bidx,
                                        Abf, Winb, Woutb, segs);
  // 1) QKV projection (bf16 MFMA) with scatter epilogue
  {
    dim3 grid(768 / 128, NROWS / 128);
    gemm_mfma<true><<<grid, 256, 0, stream>>>(Abf, Winb, b_in, nullptr,
                                              Qb, Kb, Vt, 768, DMODEL);
  }
  // 2) block-diagonal MFMA flash attention -> bf16
  attn_mfma<<<(NROWS / 16) * NHEADS / 4, 256, 0, stream>>>(Qb, Kb, Vt, bidx,
                                                           segs, attnb);
  // 3) output projection (bf16 MFMA) -> fp32
  {
    dim3 grid(DMODEL / 128, NROWS / 128);
    gemm_mfma<false><<<grid, 256, 0, stream>>>(attnb, Woutb, b_out, proj,
                                               nullptr, nullptr, nullptr,
                                               DMODEL, DMODEL);
  }
  // 4) residual + layernorm
  ln_kernel<<<NROWS, 256, 0, stream>>>(slots, proj, ln_g, ln_b, out);
}

// Round 5
// 114.935 us; speedup vs baseline: 3.3789x; 1.0510x over previous
//
#include <hip/hip_runtime.h>
#include <hip/hip_bf16.h>

#define NROWS 4096
#define DMODEL 256
#define NHEADS 8
#define HD 32

typedef __attribute__((ext_vector_type(8))) short short8;
typedef __attribute__((ext_vector_type(4))) float f32x4;

// ---------------- prep: casts (fp32->bf16) + segment bounds ----------------
__global__ __launch_bounds__(256) void prep_kernel(
    const float* __restrict__ slots, const float* __restrict__ w_in,
    const float* __restrict__ w_out, const int* __restrict__ bidx,
    __hip_bfloat16* __restrict__ Abf, __hip_bfloat16* __restrict__ Winb,
    __hip_bfloat16* __restrict__ Woutb, int* __restrict__ segs) {
  const int bid = blockIdx.x;
  const float* src;
  __hip_bfloat16* dst;
  int i;
  if (bid < 1024)      { src = slots; dst = Abf;   i = (bid * 256 + (int)threadIdx.x) * 4; }
  else if (bid < 1216) { src = w_in;  dst = Winb;  i = ((bid - 1024) * 256 + (int)threadIdx.x) * 4; }
  else if (bid < 1280) { src = w_out; dst = Woutb; i = ((bid - 1216) * 256 + (int)threadIdx.x) * 4; }
  else {
    const int r = (bid - 1280) * 256 + threadIdx.x;
    const int b = bidx[r];
    if (r == 0 || bidx[r - 1] != b) segs[b] = r;
    if (r == NROWS - 1 || bidx[r + 1] != b) segs[16 + b] = r + 1;
    return;
  }
  const float4 v = *(const float4*)(src + i);
  __hip_bfloat162 lo, hi;
  lo.x = __float2bfloat16(v.x); lo.y = __float2bfloat16(v.y);
  hi.x = __float2bfloat16(v.z); hi.y = __float2bfloat16(v.w);
  *(__hip_bfloat162*)(dst + i) = lo;
  *(__hip_bfloat162*)(dst + i + 2) = hi;
}

// ---------------- QKV GEMM: barrier-free, direct-from-global frags ---------
// 64x64 tile, 4 waves; wave wv does rows [bm+wv*16, +16) x cols [bn, bn+64).
// A/B frags loaded straight from global (16 B/lane, L1/L2-resident weights).
__global__ __launch_bounds__(256, 4) void gemm_qkv(
    const __hip_bfloat16* __restrict__ A,   // [4096][256]
    const __hip_bfloat16* __restrict__ B,   // [768][256] (w_in bf16)
    const float* __restrict__ bias,         // [768]
    __hip_bfloat16* __restrict__ Qo,        // [H][N][32]
    __hip_bfloat16* __restrict__ Ko,        // [H][N][32]
    __hip_bfloat16* __restrict__ Vo) {      // [H][32][N] (transposed)
  const int wv   = threadIdx.x >> 6;
  const int lane = threadIdx.x & 63;
  const int lo16 = lane & 15;
  const int quad = lane >> 4;
  const int bm = blockIdx.y * 64 + wv * 16;
  const int bn = blockIdx.x * 64;

  f32x4 acc[4] = {};
  #pragma unroll
  for (int k0 = 0; k0 < 256; k0 += 32) {
    const short8 af = *(const short8*)(A + (size_t)(bm + lo16) * 256 + k0 + quad * 8);
    #pragma unroll
    for (int ni = 0; ni < 4; ni++) {
      const short8 bf = *(const short8*)(B + (size_t)(bn + ni * 16 + lo16) * 256 + k0 + quad * 8);
      acc[ni] = __builtin_amdgcn_mfma_f32_16x16x32_bf16(af, bf, acc[ni], 0, 0, 0);
    }
  }
  #pragma unroll
  for (int ni = 0; ni < 4; ni++) {
    const int col = bn + ni * 16 + lo16;
    const int sel = col >> 8;          // 0:Q 1:K 2:V
    const int h = (col & 255) >> 5;
    const int d = col & 31;
    const float bv = bias[col];
    #pragma unroll
    for (int r = 0; r < 4; r++) {
      const int n = bm + quad * 4 + r;
      const __hip_bfloat16 v = __float2bfloat16(acc[ni][r] + bv);
      if (sel == 0)      Qo[((size_t)h * NROWS + n) * HD + d] = v;
      else if (sel == 1) Ko[((size_t)h * NROWS + n) * HD + d] = v;
      else               Vo[((size_t)h * HD + d) * NROWS + n] = v;
    }
  }
}

// ---------------- attention: 4-way split-K flash decoding ------------------
// One block per (q-tile of 16 rows, head). 4 waves each flash a strided
// subset of 32-col k-tiles, then LDS merge of (m, l, O).
__global__ __launch_bounds__(256, 4) void attn_mfma(
    const __hip_bfloat16* __restrict__ Qb,  // [H][N][32]
    const __hip_bfloat16* __restrict__ Kb,  // [H][N][32]
    const __hip_bfloat16* __restrict__ Vt,  // [H][32][N]
    const int* __restrict__ bidx,
    const int* __restrict__ segs,
    __hip_bfloat16* __restrict__ out)       // [N][256] bf16
{
  __shared__ __align__(16) __hip_bfloat16 Plds_all[4][16][40];
  __shared__ float mld[4][16], lld[4][16];
  __shared__ float Old[4][16][32];
  const int wv   = threadIdx.x >> 6;
  const int lane = threadIdx.x & 63;
  const int qt   = blockIdx.x >> 3;
  const int h    = blockIdx.x & 7;
  const int r0   = qt * 16;
  const int lo16 = lane & 15;
  const int quad = lane >> 4;
  __hip_bfloat16 (*Plds)[40] = Plds_all[wv];

  int st[4], en[4];
  #pragma unroll
  for (int r = 0; r < 4; r++) {
    const int b = bidx[r0 + quad * 4 + r];
    st[r] = segs[b];
    en[r] = segs[16 + b];
  }
  const int kstart = segs[bidx[r0]] & ~31;
  const int kend   = segs[16 + bidx[r0 + 15]];
  const int ntiles = (kend - kstart + 31) >> 5;

  const short8 qf = *(const short8*)(Qb + ((size_t)h * NROWS + r0 + lo16) * HD + quad * 8);

  f32x4 o0 = {0.f, 0.f, 0.f, 0.f}, o1 = {0.f, 0.f, 0.f, 0.f};
  float m[4], l[4];
  #pragma unroll
  for (int r = 0; r < 4; r++) { m[r] = -1e30f; l[r] = 0.0f; }

  const float scale = 0.17677669529663687f;  // 1/sqrt(32)

  for (int t = wv; t < ntiles; t += 4) {
    const int c0 = kstart + t * 32;
    const int col0 = c0 + lo16;
    const int col1 = col0 + 16;
    const int colc0 = min(col0, NROWS - 1);
    const int colc1 = min(col1, NROWS - 1);
    const short8 kf0 = *(const short8*)(Kb + ((size_t)h * NROWS + colc0) * HD + quad * 8);
    const short8 kf1 = *(const short8*)(Kb + ((size_t)h * NROWS + colc1) * HD + quad * 8);
    const int vc = min(c0 + quad * 8, NROWS - 8);
    const short8 vf0 = *(const short8*)(Vt + ((size_t)h * HD + lo16) * NROWS + vc);
    const short8 vf1 = *(const short8*)(Vt + ((size_t)h * HD + 16 + lo16) * NROWS + vc);

    const f32x4 z = {0.f, 0.f, 0.f, 0.f};
    f32x4 s0 = __builtin_amdgcn_mfma_f32_16x16x32_bf16(qf, kf0, z, 0, 0, 0);
    f32x4 s1 = __builtin_amdgcn_mfma_f32_16x16x32_bf16(qf, kf1, z, 0, 0, 0);

    #pragma unroll
    for (int r = 0; r < 4; r++) {
      const bool ok0 = (col0 >= st[r]) & (col0 < en[r]);
      const bool ok1 = (col1 >= st[r]) & (col1 < en[r]);
      const float sc0 = ok0 ? s0[r] * scale : -1e30f;
      const float sc1 = ok1 ? s1[r] * scale : -1e30f;
      float mx = fmaxf(sc0, sc1);
      mx = fmaxf(mx, __shfl_xor(mx, 1));
      mx = fmaxf(mx, __shfl_xor(mx, 2));
      mx = fmaxf(mx, __shfl_xor(mx, 4));
      mx = fmaxf(mx, __shfl_xor(mx, 8));
      const float nm = fmaxf(m[r], mx);
      const float alpha = __expf(m[r] - nm);
      const float p0 = ok0 ? __expf(sc0 - nm) : 0.0f;
      const float p1 = ok1 ? __expf(sc1 - nm) : 0.0f;
      float ps = p0 + p1;
      ps += __shfl_xor(ps, 1);
      ps += __shfl_xor(ps, 2);
      ps += __shfl_xor(ps, 4);
      ps += __shfl_xor(ps, 8);
      l[r] = l[r] * alpha + ps;
      m[r] = nm;
      o0[r] *= alpha;
      o1[r] *= alpha;
      Plds[quad * 4 + r][lo16]      = __float2bfloat16(p0);
      Plds[quad * 4 + r][lo16 + 16] = __float2bfloat16(p1);
    }
    const short8 pf = *(const short8*)&Plds[lo16][quad * 8];
    o0 = __builtin_amdgcn_mfma_f32_16x16x32_bf16(pf, vf0, o0, 0, 0, 0);
    o1 = __builtin_amdgcn_mfma_f32_16x16x32_bf16(pf, vf1, o1, 0, 0, 0);
  }

  // ---- publish per-wave state ----
  #pragma unroll
  for (int r = 0; r < 4; r++) {
    const int row = quad * 4 + r;
    Old[wv][row][lo16]      = o0[r];
    Old[wv][row][lo16 + 16] = o1[r];
    if (lo16 == 0) { mld[wv][row] = m[r]; lld[wv][row] = l[r]; }
  }
  __syncthreads();

  // ---- merge: thread -> (row = tid>>4, cols {c, c+16}) ----
  const int row = threadIdx.x >> 4;
  const int c   = threadIdx.x & 15;
  float M = fmaxf(fmaxf(mld[0][row], mld[1][row]),
                  fmaxf(mld[2][row], mld[3][row]));
  float L = 0.f, O0 = 0.f, O1 = 0.f;
  #pragma unroll
  for (int w = 0; w < 4; w++) {
    const float e = __expf(mld[w][row] - M);
    L  += e * lld[w][row];
    O0 += e * Old[w][row][c];
    O1 += e * Old[w][row][c + 16];
  }
  const float inv = 1.0f / L;
  const int grow = r0 + row;
  out[(size_t)grow * DMODEL + h * HD + c]      = __float2bfloat16(O0 * inv);
  out[(size_t)grow * DMODEL + h * HD + 16 + c] = __float2bfloat16(O1 * inv);
}

// ---------------- out-proj + residual + LayerNorm (fused) ------------------
// 16x256 tile (row-complete), 4 waves; wave wv does cols [wv*64, +64).
// Direct-from-global frags (w_out bf16 is 128 KB, L2-resident).
__global__ __launch_bounds__(256, 4) void gemm_out_ln(
    const __hip_bfloat16* __restrict__ A,   // attnb [4096][256]
    const __hip_bfloat16* __restrict__ B,   // w_out bf16 [256][256]
    const float* __restrict__ bias,         // b_out
    const float* __restrict__ x,            // slots fp32 (residual)
    const float* __restrict__ gamma, const float* __restrict__ beta,
    float* __restrict__ out) {
  __shared__ float red1[16][4], red2[16][4];
  const int wv   = threadIdx.x >> 6;
  const int lane = threadIdx.x & 63;
  const int lo16 = lane & 15;
  const int quad = lane >> 4;
  const int r0 = blockIdx.x * 16;
  const int wn = wv * 64;

  f32x4 acc[4] = {};
  #pragma unroll
  for (int k0 = 0; k0 < 256; k0 += 32) {
    const short8 af = *(const short8*)(A + (size_t)(r0 + lo16) * 256 + k0 + quad * 8);
    #pragma unroll
    for (int ni = 0; ni < 4; ni++) {
      const short8 bf = *(const short8*)(B + (size_t)(wn + ni * 16 + lo16) * 256 + k0 + quad * 8);
      acc[ni] = __builtin_amdgcn_mfma_f32_16x16x32_bf16(af, bf, acc[ni], 0, 0, 0);
    }
  }

  // val = delta + bias + residual; per-row partial sums across this wave
  float val[4][4];
  float s1[4] = {}, s2[4] = {};
  #pragma unroll
  for (int ni = 0; ni < 4; ni++) {
    const int col = wn + ni * 16 + lo16;
    const float bv = bias[col];
    #pragma unroll
    for (int r = 0; r < 4; r++) {
      const int row = r0 + quad * 4 + r;
      const float v = acc[ni][r] + bv + x[(size_t)row * DMODEL + col];
      val[ni][r] = v;
      s1[r] += v;
      s2[r] += v * v;
    }
  }
  #pragma unroll
  for (int r = 0; r < 4; r++) {
    #pragma unroll
    for (int off = 1; off < 16; off <<= 1) {
      s1[r] += __shfl_xor(s1[r], off);
      s2[r] += __shfl_xor(s2[r], off);
    }
    if (lo16 == 0) { red1[quad * 4 + r][wv] = s1[r]; red2[quad * 4 + r][wv] = s2[r]; }
  }
  __syncthreads();
  #pragma unroll
  for (int r = 0; r < 4; r++) {
    const int lrow = quad * 4 + r;
    const float mean = (red1[lrow][0] + red1[lrow][1] + red1[lrow][2] + red1[lrow][3]) * (1.0f / DMODEL);
    const float ex2  = (red2[lrow][0] + red2[lrow][1] + red2[lrow][2] + red2[lrow][3]) * (1.0f / DMODEL);
    const float rstd = rsqrtf(fmaxf(ex2 - mean * mean, 0.0f) + 1e-5f);
    const int row = r0 + lrow;
    #pragma unroll
    for (int ni = 0; ni < 4; ni++) {
      const int col = wn + ni * 16 + lo16;
      out[(size_t)row * DMODEL + col] =
          (val[ni][r] - mean) * rstd * gamma[col] + beta[col];
    }
  }
}

extern "C" void kernel_launch(void* const* d_in, const int* in_sizes, int n_in,
                              void* d_out, int out_size, void* d_ws, size_t ws_size,
                              hipStream_t stream) {
  const float* slots  = (const float*)d_in[0];
  const int*   bidx   = (const int*)  d_in[1];
  const float* w_in   = (const float*)d_in[2];
  const float* b_in   = (const float*)d_in[3];
  const float* w_out  = (const float*)d_in[4];
  const float* b_out  = (const float*)d_in[5];
  const float* ln_g   = (const float*)d_in[6];
  const float* ln_b   = (const float*)d_in[7];
  float* out = (float*)d_out;

  char* ws = (char*)d_ws;
  __hip_bfloat16* Abf   = (__hip_bfloat16*)(ws);                 // 2 MB
  __hip_bfloat16* Qb    = (__hip_bfloat16*)(ws + (2u  << 20));   // 2 MB
  __hip_bfloat16* Kb    = (__hip_bfloat16*)(ws + (4u  << 20));   // 2 MB
  __hip_bfloat16* Vt    = (__hip_bfloat16*)(ws + (6u  << 20));   // 2 MB
  __hip_bfloat16* attnb = (__hip_bfloat16*)(ws + (8u  << 20));   // 2 MB
  __hip_bfloat16* Winb  = (__hip_bfloat16*)(ws + (10u << 20));   // 384 KB
  __hip_bfloat16* Woutb = (__hip_bfloat16*)(ws + (10u << 20) + (512u << 10)); // 128 KB
  int*            segs  = (int*)           (ws + (11u << 20));   // 32 ints

  // 0) fused casts + segment bounds
  prep_kernel<<<1296, 256, 0, stream>>>(slots, w_in, w_out, bidx,
                                        Abf, Winb, Woutb, segs);
  // 1) QKV projection -> scattered Q/K/Vt (bf16), 768 blocks
  {
    dim3 grid(768 / 64, NROWS / 64);
    gemm_qkv<<<grid, 256, 0, stream>>>(Abf, Winb, b_in, Qb, Kb, Vt);
  }
  // 2) split-K flash attention, one block per (q-tile, head)
  attn_mfma<<<(NROWS / 16) * NHEADS, 256, 0, stream>>>(Qb, Kb, Vt, bidx,
                                                       segs, attnb);
  // 3) out-proj + residual + LayerNorm, 256 blocks
  gemm_out_ln<<<NROWS / 16, 256, 0, stream>>>(attnb, Woutb, b_out, slots,
                                              ln_g, ln_b, out);
}